// Round 5
// baseline (2100.382 us; speedup 1.0000x reference)
//
#include <hip/hip_runtime.h>
#include <hip/hip_bf16.h>
#include <float.h>

#define K_NN 20
#define EPS 1e-5f
#define SLOPE 0.2f
constexpr int Bsz = 8;
constexpr int Npts = 2048;
constexpr int NQ = 8;            // layer-1 knn candidate-quadrant split
constexpr int BN = Bsz * Npts;   // 16384

typedef __attribute__((ext_vector_type(8))) short short8v;
typedef __attribute__((ext_vector_type(4))) float f32x4;

__device__ __forceinline__ float dot4(float4 a, float4 b) {
  return a.x*b.x + a.y*b.y + a.z*b.z + a.w*b.w;
}
// order-preserving float<->uint encoding for atomicMax pooling (exact, deterministic)
__device__ __forceinline__ unsigned encf(float f) {
  unsigned u = __float_as_uint(f);
  return (u & 0x80000000u) ? ~u : (u | 0x80000000u);
}
__device__ __forceinline__ float decf(unsigned e) {
  unsigned u = (e & 0x80000000u) ? (e & 0x7fffffffu) : ~e;
  return __uint_as_float(u);
}
// bf16 split helpers (RNE)
__device__ __forceinline__ unsigned short f2bf(float x) {
  unsigned u = __float_as_uint(x);
  unsigned r = (u + 0x7fffu + ((u >> 16) & 1u)) >> 16;
  return (unsigned short)r;
}
__device__ __forceinline__ float bf2f(unsigned short h) {
  return __uint_as_float((unsigned)h << 16);
}
__device__ __forceinline__ f32x4 mfma16(short8v a, short8v b, f32x4 c) {
  return __builtin_amdgcn_mfma_f32_16x16x32_bf16(a, b, c, 0, 0, 0);
}

// ---------------------------------------------------------------- sq of rows
template<int C>
__global__ __launch_bounds__(256) void sq_kernel(const float* __restrict__ xt,
                                                 float* __restrict__ sq) {
  int p = blockIdx.x * 256 + threadIdx.x;
  if (p >= BN) return;
  const float* r = xt + (size_t)p * C;
  float s = 0.f;
  if constexpr (C % 4 == 0) {
    for (int c4 = 0; c4 < C / 4; ++c4) { float4 v = *(const float4*)(r + c4 * 4); s += dot4(v, v); }
  } else {
    #pragma unroll
    for (int c = 0; c < C; ++c) { float v = r[c]; s += v * v; }
  }
  sq[p] = s;
}

// ------------------------------------------------- layer-1 knn partial top-k (C=3)
template<int C, int MT>
__global__ __launch_bounds__(256) void knn_part(const float* __restrict__ xt,
    const float* __restrict__ sq, float* __restrict__ pval, int* __restrict__ pidx) {
  constexpr int MQ = Npts / NQ;
  __shared__ __align__(16) float chk[MT][C];
  __shared__ float csq[MT];
  const int t = threadIdx.x, w = t >> 6, l = t & 63;
  const int rowblk = blockIdx.x / NQ;
  const int q = blockIdx.x - rowblk * NQ;
  const int p0 = rowblk * 256;
  const int b = p0 / Npts;
  const int myrow = p0 + w * 64 + l;

  float cr[C];
  #pragma unroll
  for (int c = 0; c < C; ++c) cr[c] = xt[(size_t)myrow * C + c];
  const float sqn = sq[myrow];

  float vals[K_NN]; int ids[K_NN];
  #pragma unroll
  for (int i = 0; i < K_NN; ++i) { vals[i] = -FLT_MAX; ids[i] = 0; }

  const int mbase = q * MQ;
  for (int m0 = mbase; m0 < mbase + MQ; m0 += MT) {
    __syncthreads();
    const float* s2 = xt + ((size_t)b * Npts + m0) * C;
    for (int e = t; e < MT * C; e += 256) chk[e / C][e - (e / C) * C] = s2[e];
    for (int e = t; e < MT; e += 256) csq[e] = sq[b * Npts + m0 + e];
    __syncthreads();
    for (int j = 0; j < MT; ++j) {
      float dt = 0.f;
      #pragma unroll
      for (int c = 0; c < C; ++c) dt += cr[c] * chk[j][c];
      float nd = 2.f * dt - sqn - csq[j];
      if (nd > vals[K_NN - 1]) {          // strict: ties keep earlier (lower) index
        vals[K_NN - 1] = nd; ids[K_NN - 1] = m0 + j;
        #pragma unroll
        for (int i = K_NN - 1; i >= 1; --i) {
          if (vals[i] > vals[i - 1]) {
            float tv = vals[i]; vals[i] = vals[i-1]; vals[i-1] = tv;
            int ti = ids[i]; ids[i] = ids[i-1]; ids[i-1] = ti;
          }
        }
      }
    }
  }
  size_t base = ((size_t)q * BN + myrow) * K_NN;
  #pragma unroll
  for (int i = 0; i < K_NN; ++i) { pval[base + i] = vals[i]; pidx[base + i] = ids[i]; }
}

// ------------------------------------------------- merge NQ sorted lists -> top-20
__global__ __launch_bounds__(256) void knn_merge(const float* __restrict__ pval,
    const int* __restrict__ pidx, int* __restrict__ idxout) {
  int p = blockIdx.x * 256 + threadIdx.x;
  if (p >= BN) return;
  float vals[K_NN]; int ids[K_NN];
  size_t base = (size_t)p * K_NN;
  #pragma unroll
  for (int i = 0; i < K_NN; ++i) { vals[i] = pval[base + i]; ids[i] = pidx[base + i]; }
  for (int q = 1; q < NQ; ++q) {
    size_t b2 = ((size_t)q * BN + p) * K_NN;
    #pragma unroll
    for (int i = 0; i < K_NN; ++i) {
      float v = pval[b2 + i];
      if (v <= vals[K_NN - 1]) break;
      int m = pidx[b2 + i];
      vals[K_NN - 1] = v; ids[K_NN - 1] = m;
      #pragma unroll
      for (int r = K_NN - 1; r >= 1; --r) {
        if (vals[r] > vals[r - 1]) {
          float tv = vals[r]; vals[r] = vals[r-1]; vals[r-1] = tv;
          int ti = ids[r]; ids[r] = ids[r-1]; ids[r-1] = ti;
        }
      }
    }
  }
  int* op = idxout + (size_t)p * K_NN;
  #pragma unroll
  for (int i = 0; i < K_NN; ++i) op[i] = ids[i];
}

// ------------------------------------------------- MFMA distance GEMM (split-bf16)
// Tile 64x64, 4 waves = 4 col-tiles. nd[bb][n][m] = 2*X_n.X_m - sq_n - sq_m, diag=0.
template<int C>
__global__ __launch_bounds__(256) void dist_mfma(
    const unsigned short* __restrict__ xh, const unsigned short* __restrict__ xl,
    const float* __restrict__ sq, float* __restrict__ nd, int b0) {
  constexpr int KS = C / 32;
  const int bid = blockIdx.x;
  const int bb = bid >> 10;                 // (2048/64)^2 = 1024 tiles per batch
  const int tile = bid & 1023;
  const int nt = tile >> 5, mt = tile & 31;
  const int b = b0 + bb;
  const int t = threadIdx.x, l = t & 63, wv = t >> 6;
  const int l15 = l & 15, grp = l >> 4;
  const int n0 = nt * 64, m0 = mt * 64;
  const unsigned short* xbh = xh + (size_t)b * Npts * C;
  const unsigned short* xbl = xl + (size_t)b * Npts * C;
  const int mcol = m0 + wv * 16 + l15;

  f32x4 acc[4];
  #pragma unroll
  for (int rt = 0; rt < 4; ++rt) acc[rt] = (f32x4){0.f, 0.f, 0.f, 0.f};

  #pragma unroll
  for (int ks = 0; ks < KS; ++ks) {
    const int krd = ks * 32 + grp * 8;
    const short8v bh = *(const short8v*)(xbh + (size_t)mcol * C + krd);
    const short8v bl = *(const short8v*)(xbl + (size_t)mcol * C + krd);
    #pragma unroll
    for (int rt = 0; rt < 4; ++rt) {
      const int arow = n0 + rt * 16 + l15;
      const short8v ah = *(const short8v*)(xbh + (size_t)arow * C + krd);
      const short8v al = *(const short8v*)(xbl + (size_t)arow * C + krd);
      acc[rt] = mfma16(ah, bh, acc[rt]);
      acc[rt] = mfma16(al, bh, acc[rt]);
      acc[rt] = mfma16(ah, bl, acc[rt]);
    }
  }
  const float sqm = sq[b * Npts + mcol];
  #pragma unroll
  for (int rt = 0; rt < 4; ++rt) {
    #pragma unroll
    for (int r = 0; r < 4; ++r) {
      const int n = n0 + rt * 16 + grp * 4 + r;
      float v = 2.f * acc[rt][r] - sq[b * Npts + n] - sqm;
      if (n == mcol) v = 0.f;               // exact self-distance
      nd[((size_t)bb * Npts + n) * Npts + mcol] = v;
    }
  }
}

// ------------------------------------------------- top-20 select from nd rows
// 1-wave blocks: 4 rows x 16 scanners; float4 loads (16 lanes = 1KB contiguous);
// per-thread sorted top-20 over its 128 cols, then 4 lanes merge 16 lists each.
__global__ __launch_bounds__(64) void knn_select(const float* __restrict__ nd,
    int* __restrict__ idxout, int b0) {
  constexpr int RPB = 4;
  __shared__ float svals[64][K_NN];
  __shared__ int   sids [64][K_NN];
  const int t = threadIdx.x;
  const int row = t >> 4, s = t & 15;
  const int bb = blockIdx.x >> 9, rb = blockIdx.x & 511;   // 1024 blocks per 2-batch call
  const int n = rb * RPB + row;
  const float* ndr = nd + ((size_t)bb * Npts + n) * Npts;

  float vals[K_NN]; int ids[K_NN];
  #pragma unroll
  for (int i = 0; i < K_NN; ++i) { vals[i] = -FLT_MAX; ids[i] = 0; }
  #pragma unroll 4
  for (int i = 0; i < Npts / 64; ++i) {
    const int cb = (i * 16 + s) * 4;
    const float4 v4 = *(const float4*)(ndr + cb);
    float vq[4] = {v4.x, v4.y, v4.z, v4.w};
    #pragma unroll
    for (int q = 0; q < 4; ++q) {
      const float v = vq[q];
      if (v > vals[K_NN - 1]) {            // strict: ties keep earlier (lower) index
        vals[K_NN - 1] = v; ids[K_NN - 1] = cb + q;
        #pragma unroll
        for (int r = K_NN - 1; r >= 1; --r) {
          if (vals[r] > vals[r - 1]) {
            float tv = vals[r]; vals[r] = vals[r-1]; vals[r-1] = tv;
            int ti = ids[r]; ids[r] = ids[r-1]; ids[r-1] = ti;
          }
        }
      }
    }
  }
  #pragma unroll
  for (int i = 0; i < K_NN; ++i) { svals[t][i] = vals[i]; sids[t][i] = ids[i]; }
  __syncthreads();
  if (t < RPB) {
    float mv[K_NN]; int mi[K_NN];
    const int base0 = t * 16;
    #pragma unroll
    for (int i = 0; i < K_NN; ++i) { mv[i] = svals[base0][i]; mi[i] = sids[base0][i]; }
    for (int s2 = 1; s2 < 16; ++s2) {
      const int bs = base0 + s2;
      #pragma unroll
      for (int i = 0; i < K_NN; ++i) {
        const float v = svals[bs][i];
        if (v <= mv[K_NN - 1]) break;      // sorted source -> rest also fail
        const int m = sids[bs][i];
        mv[K_NN - 1] = v; mi[K_NN - 1] = m;
        #pragma unroll
        for (int r = K_NN - 1; r >= 1; --r) {
          if (mv[r] > mv[r - 1]) {
            float tv = mv[r]; mv[r] = mv[r-1]; mv[r-1] = tv;
            int ti = mi[r]; mi[r] = mi[r-1]; mi[r-1] = ti;
          }
        }
      }
    }
    int* op = idxout + ((size_t)((b0 + bb) * Npts + rb * RPB + t)) * K_NN;
    #pragma unroll
    for (int i = 0; i < K_NN; ++i) op[i] = mi[i];
  }
}

// ------------------------------------------------- prep: split weights to bf16 pairs
template<int C, int O>
__global__ __launch_bounds__(256) void prep_w(const float* __restrict__ W,
    unsigned short* __restrict__ wlh, unsigned short* __restrict__ wll,
    unsigned short* __restrict__ dhh, unsigned short* __restrict__ dll) {
  int i = blockIdx.x * 256 + threadIdx.x;
  if (i >= O * C) return;
  int o = i / C, c = i - o * C;
  float wl = W[(size_t)o * 2 * C + c];
  float wh = W[(size_t)o * 2 * C + C + c];
  float d = wh - wl;
  unsigned short h1 = f2bf(wl);
  wlh[i] = h1; wll[i] = f2bf(wl - bf2f(h1));
  unsigned short h2 = f2bf(d);
  dhh[i] = h2; dll[i] = f2bf(d - bf2f(h2));
}

// ------------------------------------------------- MFMA edge conv (split-bf16, 3-term)
// Inputs pre-split bf16. P=4 points/block; rows 0..79 neighbors, 80..83 centers.
// LDS tiles XOR-swizzled in 16B chunks: chunk kc stored at kc ^ (row & 7).
template<int C, int O>
__global__ __launch_bounds__(256, 2) void edge_mfma(
    const unsigned short* __restrict__ xh, const unsigned short* __restrict__ xl,
    const int* __restrict__ idx,
    const unsigned short* __restrict__ wlh, const unsigned short* __restrict__ wll,
    const unsigned short* __restrict__ dhh, const unsigned short* __restrict__ dll,
    float* __restrict__ mx, float* __restrict__ mn,
    float* __restrict__ psum, float* __restrict__ psq) {
  constexpr int P = 4, RTM = 5, RT = 6, NROW = 96;
  constexpr int KS = C / 32;
  constexpr int CTW = O / 64;
  constexpr int NCH = C / 8;                   // 16B chunks per row
  __shared__ __align__(16) unsigned short Ah[NROW][C];
  __shared__ __align__(16) unsigned short Al[NROW][C];
  __shared__ int ids_s[NROW];
  const int t = threadIdx.x;
  const int p0 = blockIdx.x * P;

  if (t < NROW) {
    int id;
    if (t < P * K_NN) {
      int p = t / K_NN, k = t - p * K_NN;
      int b = p0 / Npts;
      id = b * Npts + idx[(size_t)(p0 + p) * K_NN + k];
    } else if (t < P * K_NN + P) id = p0 + (t - P * K_NN);
    else id = -1;
    ids_s[t] = id;
  }
  __syncthreads();
  for (int e = t; e < NROW * NCH; e += 256) {
    int row = e / NCH, kc = e - row * NCH;
    int id = ids_s[row];
    short8v vh = {0,0,0,0,0,0,0,0}, vl = {0,0,0,0,0,0,0,0};
    if (id >= 0) {
      vh = *(const short8v*)(xh + (size_t)id * C + kc * 8);
      vl = *(const short8v*)(xl + (size_t)id * C + kc * 8);
    }
    const int kcs = (kc ^ (row & 7)) * 8;
    *(short8v*)(&Ah[row][kcs]) = vh;
    *(short8v*)(&Al[row][kcs]) = vl;
  }
  __syncthreads();

  const int l = t & 63, wv = t >> 6;
  const int grp = l >> 4, l15 = l & 15;
  f32x4 acc[RT][CTW];
  #pragma unroll
  for (int rt = 0; rt < RT; ++rt)
    #pragma unroll
    for (int j = 0; j < CTW; ++j) acc[rt][j] = (f32x4){0.f, 0.f, 0.f, 0.f};

  for (int ks = 0; ks < KS; ++ks) {
    const int kc = ks * 4 + grp;
    short8v ah[RT], al[RT];
    #pragma unroll
    for (int rt = 0; rt < RT; ++rt) {
      const int row = rt * 16 + l15;
      const int kcs = (kc ^ (row & 7)) * 8;
      ah[rt] = *(const short8v*)(&Ah[row][kcs]);
      al[rt] = *(const short8v*)(&Al[row][kcs]);
    }
    const int krd = ks * 32 + grp * 8;
    #pragma unroll
    for (int j = 0; j < CTW; ++j) {
      const int col = (wv * CTW + j) * 16 + l15;
      const size_t boff = (size_t)col * C + krd;
      short8v bh = *(const short8v*)(wlh + boff);
      short8v bl = *(const short8v*)(wll + boff);
      #pragma unroll
      for (int rt = 0; rt < RTM; ++rt) {
        acc[rt][j] = mfma16(ah[rt], bh, acc[rt][j]);
        acc[rt][j] = mfma16(ah[rt], bl, acc[rt][j]);
        acc[rt][j] = mfma16(al[rt], bh, acc[rt][j]);
      }
      short8v ch = *(const short8v*)(dhh + boff);
      short8v cl = *(const short8v*)(dll + boff);
      acc[RTM][j] = mfma16(ah[RTM], ch, acc[RTM][j]);
      acc[RTM][j] = mfma16(ah[RTM], cl, acc[RTM][j]);
      acc[RTM][j] = mfma16(al[RTM], ch, acc[RTM][j]);
    }
  }

  // center term: ctr-tile row p is in reg p of grp0 lanes (same wave, lane l15)
  #pragma unroll
  for (int j = 0; j < CTW; ++j) {
    const int col = (wv * CTW + j) * 16 + l15;
    const float bp0 = __shfl(acc[RTM][j][0], l15);
    const float bp1 = __shfl(acc[RTM][j][1], l15);
    const float bp2 = __shfl(acc[RTM][j][2], l15);
    const float bp3 = __shfl(acc[RTM][j][3], l15);
    float bsel[RTM];
    bsel[0] = bp0;
    bsel[1] = (1 <= grp) ? bp1 : bp0;
    bsel[2] = (2 <= grp) ? bp2 : bp1;
    bsel[3] = (3 <= grp) ? bp3 : bp2;
    bsel[4] = bp3;
    float pmx[RTM], pmn[RTM];
    float lsum = 0.f, lsq = 0.f;
    #pragma unroll
    for (int rt = 0; rt < RTM; ++rt) {
      float y0 = acc[rt][j][0] + bsel[rt];
      float y1 = acc[rt][j][1] + bsel[rt];
      float y2 = acc[rt][j][2] + bsel[rt];
      float y3 = acc[rt][j][3] + bsel[rt];
      lsum += (y0 + y1) + (y2 + y3);
      lsq = fmaf(y0, y0, lsq); lsq = fmaf(y1, y1, lsq);
      lsq = fmaf(y2, y2, lsq); lsq = fmaf(y3, y3, lsq);
      pmx[rt] = fmaxf(fmaxf(y0, y1), fmaxf(y2, y3));
      pmn[rt] = fminf(fminf(y0, y1), fminf(y2, y3));
    }
    #pragma unroll
    for (int p = 0; p < P; ++p) {
      float xm = (p <= grp) ? pmx[p] : pmx[p + 1];
      float fm = (p == grp) ? fmaxf(xm, pmx[p + 1]) : xm;
      float xn = (p <= grp) ? pmn[p] : pmn[p + 1];
      float fn = (p == grp) ? fminf(xn, pmn[p + 1]) : xn;
      fm = fmaxf(fm, __shfl_xor(fm, 16)); fm = fmaxf(fm, __shfl_xor(fm, 32));
      fn = fminf(fn, __shfl_xor(fn, 16)); fn = fminf(fn, __shfl_xor(fn, 32));
      if (grp == 0) {
        size_t ob = (size_t)(p0 + p) * O + col;
        mx[ob] = fm; mn[ob] = fn;
      }
    }
    lsum += __shfl_xor(lsum, 16); lsum += __shfl_xor(lsum, 32);
    lsq  += __shfl_xor(lsq , 16); lsq  += __shfl_xor(lsq , 32);
    if (grp == 0) {
      psum[(size_t)blockIdx.x * O + col] = lsum;
      psq [(size_t)blockIdx.x * O + col] = lsq;
    }
  }
}

// ------------------------------------------------- vector edge conv (layer 1, C=3)
template<int C, int O, int G, int NPG, int CPT>
__global__ __launch_bounds__(256) void edge_kernel(const float* __restrict__ xt,
    const int* __restrict__ idx, const float* __restrict__ W,
    float* __restrict__ mx, float* __restrict__ mn,
    float* __restrict__ psum, float* __restrict__ psq) {
  constexpr int WP = O / (64 * CPT);
  constexpr int TPB = 64 * WP * NPG;
  constexpr int PPG = G / NPG;
  static_assert(TPB == 256, "block must be 256 threads");
  __shared__ __align__(16) float pts[G][K_NN + 1][C];
  __shared__ int ids[G][K_NN + 1];
  __shared__ float shps[NPG][O];
  __shared__ float shpq[NPG][O];
  const int t = threadIdx.x;
  const int p0 = blockIdx.x * G;
  const int b = p0 / Npts;

  for (int e = t; e < G * (K_NN + 1); e += TPB) {
    int g = e / (K_NN + 1), j = e - g * (K_NN + 1);
    ids[g][j] = (j == 0) ? (p0 + g) : (b * Npts + idx[(size_t)(p0 + g) * K_NN + (j - 1)]);
  }
  __syncthreads();
  for (int e = t; e < G * (K_NN + 1) * C; e += TPB) {
    int g = e / ((K_NN + 1) * C), rem = e - g * ((K_NN + 1) * C);
    int j = rem / C, c = rem - j * C;
    pts[g][j][c] = xt[(size_t)ids[g][j] * C + c];
  }
  __syncthreads();

  const int w = t >> 6, l = t & 63;
  const int pg = w / WP, wp = w - pg * WP;
  const int o0 = wp * 64 + l;
  float ls0 = 0.f, lq0 = 0.f;

  for (int it = 0; it < PPG; ++it) {
    const int g = pg * PPG + it;
    float yk0[K_NN];
    float u0 = 0.f, v0 = 0.f;
    #pragma unroll
    for (int k = 0; k < K_NN; ++k) yk0[k] = 0.f;
    const float* W0 = W + (size_t)o0 * (2 * C);
    #pragma unroll
    for (int c = 0; c < C; ++c) {
      const float wl = W0[c], wh = W0[C + c], ccv = pts[g][0][c];
      u0 += wl * ccv; v0 += wh * ccv;
      #pragma unroll
      for (int k = 0; k < K_NN; ++k) yk0[k] += wl * pts[g][k + 1][c];
    }
    const int n = p0 + g - b * Npts;
    const size_t obase = ((size_t)b * Npts + n) * O;
    const float base = v0 - u0;
    float vmx = -FLT_MAX, vmn = FLT_MAX;
    #pragma unroll
    for (int k = 0; k < K_NN; ++k) {
      float y = yk0[k] + base;
      ls0 += y; lq0 += y * y;
      vmx = fmaxf(vmx, y); vmn = fminf(vmn, y);
    }
    mx[obase + o0] = vmx; mn[obase + o0] = vmn;
  }

  shps[pg][o0] = ls0; shpq[pg][o0] = lq0;
  __syncthreads();
  if (t < O) {
    float s = 0.f, qq = 0.f;
    #pragma unroll
    for (int i = 0; i < NPG; ++i) { s += shps[i][t]; qq += shpq[i][t]; }
    psum[(size_t)blockIdx.x * O + t] = s;
    psq [(size_t)blockIdx.x * O + t] = qq;
  }
}

// ------------------------------------------------- two-stage BN stats
template<int O, int NBLK>
__global__ __launch_bounds__(256) void stats_part(const float* __restrict__ psum,
    const float* __restrict__ psq, double* __restrict__ pp, double* __restrict__ pq) {
  constexpr int NS = 16;
  constexpr int SL = NBLK / NS;
  const int l = threadIdx.x & 63, w = threadIdx.x >> 6;
  const int os = blockIdx.x % (O / 64), sl = blockIdx.x / (O / 64);
  const int o = os * 64 + l;
  double s = 0.0, ss = 0.0;
  for (int i = sl * SL + w; i < (sl + 1) * SL; i += 4) {
    s  += (double)psum[(size_t)i * O + o];
    ss += (double)psq [(size_t)i * O + o];
  }
  __shared__ double sh[2][4][64];
  sh[0][w][l] = s; sh[1][w][l] = ss;
  __syncthreads();
  if (w == 0) {
    s  = sh[0][0][l] + sh[0][1][l] + sh[0][2][l] + sh[0][3][l];
    ss = sh[1][0][l] + sh[1][1][l] + sh[1][2][l] + sh[1][3][l];
    pp[(size_t)sl * O + o] = s;
    pq[(size_t)sl * O + o] = ss;
  }
}

template<int O>
__global__ __launch_bounds__(64) void stats_final(const double* __restrict__ pp,
    const double* __restrict__ pq,
    const float* __restrict__ gamma, const float* __restrict__ beta,
    float* __restrict__ scale, float* __restrict__ bias) {
  const int o = blockIdx.x * 64 + threadIdx.x;
  double s = 0.0, ss = 0.0;
  #pragma unroll
  for (int sl = 0; sl < 16; ++sl) { s += pp[(size_t)sl * O + o]; ss += pq[(size_t)sl * O + o]; }
  double cnt = (double)Bsz * Npts * K_NN;
  double m = s / cnt;
  double var = ss / cnt - m * m;
  float g = gamma[o];
  float sc = g * rsqrtf((float)var + EPS);
  scale[o] = sc;
  bias[o] = beta[o] - (float)m * sc;
}

// ------------------------------------------------- reset pooled accumulators
__global__ __launch_bounds__(256) void reset_pool(unsigned* __restrict__ pooled) {
  int i = blockIdx.x * 256 + threadIdx.x;
  if (i < Bsz * 448) pooled[i] = 0u;   // 0 < encf(f) for all finite f
}

// ------------------------------------------------- normalize + lrelu + pool + bf16 split
template<int O, int COFF, bool WNC>
__global__ __launch_bounds__(256) void apply_kernel(const float* __restrict__ mx,
    const float* __restrict__ mn, const float* __restrict__ scale,
    const float* __restrict__ bias, float* __restrict__ xnc,
    unsigned short* __restrict__ xh, unsigned short* __restrict__ xl,
    unsigned* __restrict__ pooled) {
  constexpr int OT = O / 64;
  constexpr int NCH = Npts / 256;
  const int bid = blockIdx.x;
  const int nchunk = bid % NCH;
  const int ot = (bid / NCH) % OT;
  const int b = bid / (NCH * OT);
  const int l = threadIdx.x & 63, w = threadIdx.x >> 6;
  const int o = ot * 64 + l;
  const float sc = scale[o], bs = bias[o];
  const bool pos = (sc >= 0.f);
  float vmax = -FLT_MAX;
  const int n0 = nchunk * 256;
  for (int i = 0; i < 64; ++i) {
    int n = n0 + w + i * 4;
    size_t ix = ((size_t)b * Npts + n) * O + o;
    float raw = pos ? mx[ix] : mn[ix];   // max for +scale, min for -scale
    float y = raw * sc + bs;
    y = (y >= 0.f) ? y : SLOPE * y;
    if constexpr (WNC) {
      xnc[ix] = y;
      unsigned short h = f2bf(y);
      xh[ix] = h;
      xl[ix] = f2bf(y - bf2f(h));
    }
    vmax = fmaxf(vmax, y);
  }
  __shared__ float sh[4][64];
  sh[w][l] = vmax;
  __syncthreads();
  if (w == 0) {
    float m = fmaxf(fmaxf(sh[0][l], sh[1][l]), fmaxf(sh[2][l], sh[3][l]));
    atomicMax(pooled + b * 448 + COFF + o, encf(m));
  }
}

// ------------------------------------------------- FC layers
template<int CIN, bool LRELU, bool DECODE>
__global__ __launch_bounds__(64) void fc_kernel(const void* __restrict__ inv,
    const float* __restrict__ Wt, float* __restrict__ out, int JO) {
  int j = blockIdx.x;
  const float* wr = Wt + (size_t)j * CIN;
  float acc[Bsz];
  #pragma unroll
  for (int b = 0; b < Bsz; ++b) acc[b] = 0.f;
  for (int c = threadIdx.x; c < CIN; c += 64) {
    float wv = wr[c];
    #pragma unroll
    for (int b = 0; b < Bsz; ++b) {
      float x;
      if constexpr (DECODE) x = decf(((const unsigned*)inv)[b * CIN + c]);
      else                  x = ((const float*)inv)[b * CIN + c];
      acc[b] += x * wv;
    }
  }
  #pragma unroll
  for (int b = 0; b < Bsz; ++b) {
    float v = acc[b];
    #pragma unroll
    for (int w = 32; w > 0; w >>= 1) v += __shfl_down(v, w);
    if (threadIdx.x == 0) {
      if (LRELU) v = (v >= 0.f) ? v : SLOPE * v;
      out[b * JO + j] = v;
    }
  }
}

// ================================================================ launch
extern "C" void kernel_launch(void* const* d_in, const int* in_sizes, int n_in,
                              void* d_out, int out_size, void* d_ws, size_t ws_size,
                              hipStream_t stream) {
  const float* x   = (const float*)d_in[0];
  const float* W1  = (const float*)d_in[1];
  const float* g1  = (const float*)d_in[2];
  const float* b1  = (const float*)d_in[3];
  const float* W2  = (const float*)d_in[4];
  const float* g2  = (const float*)d_in[5];
  const float* b2  = (const float*)d_in[6];
  const float* W3  = (const float*)d_in[7];
  const float* g3  = (const float*)d_in[8];
  const float* b3  = (const float*)d_in[9];
  const float* L1  = (const float*)d_in[10];
  const float* L2  = (const float*)d_in[11];
  float* out = (float*)d_out;

  float* ws = (float*)d_ws;
  size_t off = 0;
  float* sq    = ws + off; off += BN;
  int*   idxb  = (int*)(ws + off); off += (size_t)BN * K_NN;
  float* mx    = ws + off; off += (size_t)BN * 256;
  float* mn    = ws + off; off += (size_t)BN * 256;
  float* psum  = ws + off; off += (size_t)4096 * 256;
  float* psq   = ws + off; off += (size_t)4096 * 256;
  off = (off + 1) & ~(size_t)1;   // 8B align for doubles
  double* pp   = (double*)(ws + off); off += 16 * 256 * 2;
  double* pq   = (double*)(ws + off); off += 16 * 256 * 2;
  float* scale = ws + off; off += 256;
  float* bias  = ws + off; off += 256;
  float* x1nc  = ws + off; off += (size_t)BN * 64;
  float* x2nc  = ws + off; off += (size_t)BN * 128;
  unsigned short* xh1 = (unsigned short*)(ws + off); off += (size_t)BN * 64 / 2;
  unsigned short* xl1 = (unsigned short*)(ws + off); off += (size_t)BN * 64 / 2;
  unsigned short* xh2 = (unsigned short*)(ws + off); off += (size_t)BN * 128 / 2;
  unsigned short* xl2 = (unsigned short*)(ws + off); off += (size_t)BN * 128 / 2;
  unsigned* pooled = (unsigned*)(ws + off); off += Bsz * 448;
  float* h     = ws + off; off += Bsz * 1024;
  unsigned short* wlh2 = (unsigned short*)(ws + off); off += 128 * 64 / 2;
  unsigned short* wll2 = (unsigned short*)(ws + off); off += 128 * 64 / 2;
  unsigned short* dh2  = (unsigned short*)(ws + off); off += 128 * 64 / 2;
  unsigned short* dl2  = (unsigned short*)(ws + off); off += 128 * 64 / 2;
  unsigned short* wlh3 = (unsigned short*)(ws + off); off += 256 * 128 / 2;
  unsigned short* wll3 = (unsigned short*)(ws + off); off += 256 * 128 / 2;
  unsigned short* dh3  = (unsigned short*)(ws + off); off += 256 * 128 / 2;
  unsigned short* dl3  = (unsigned short*)(ws + off); off += 256 * 128 / 2;
  // overlays on mx/mn (disjoint lifetimes): layer-1 partial lists, layer-2/3 nd
  float* pval = mx;
  int*   pidx = (int*)mn;
  float* nd   = mx;   // 2 batches x 2048 x 2048 fp32 = mx+mn exactly

  reset_pool<<<14, 256, 0, stream>>>(pooled);
  prep_w<64, 128><<<(128 * 64 + 255) / 256, 256, 0, stream>>>(W2, wlh2, wll2, dh2, dl2);
  prep_w<128, 256><<<(256 * 128 + 255) / 256, 256, 0, stream>>>(W3, wlh3, wll3, dh3, dl3);

  // ---- edge block 1: C=3 -> O=64 (fp32 vector knn + conv)
  sq_kernel<3><<<64, 256, 0, stream>>>(x, sq);
  knn_part<3, 64><<<(BN / 256) * NQ, 256, 0, stream>>>(x, sq, pval, pidx);
  knn_merge<<<64, 256, 0, stream>>>(pval, pidx, idxb);
  edge_kernel<3, 64, 16, 4, 1><<<BN / 16, 256, 0, stream>>>(x, idxb, W1, mx, mn, psum, psq);
  stats_part<64, 1024><<<16, 256, 0, stream>>>(psum, psq, pp, pq);
  stats_final<64><<<1, 64, 0, stream>>>(pp, pq, g1, b1, scale, bias);
  apply_kernel<64, 0, true><<<64, 256, 0, stream>>>(mx, mn, scale, bias, x1nc, xh1, xl1, pooled);

  // ---- edge block 2: C=64 -> O=128 (MFMA knn + conv)
  sq_kernel<64><<<64, 256, 0, stream>>>(x1nc, sq);
  for (int it = 0; it < 4; ++it) {
    dist_mfma<64><<<2048, 256, 0, stream>>>(xh1, xl1, sq, nd, it * 2);
    knn_select<<<1024, 64, 0, stream>>>(nd, idxb, it * 2);
  }
  edge_mfma<64, 128><<<BN / 4, 256, 0, stream>>>(xh1, xl1, idxb, wlh2, wll2, dh2, dl2,
                                                 mx, mn, psum, psq);
  stats_part<128, 4096><<<32, 256, 0, stream>>>(psum, psq, pp, pq);
  stats_final<128><<<2, 64, 0, stream>>>(pp, pq, g2, b2, scale, bias);
  apply_kernel<128, 64, true><<<128, 256, 0, stream>>>(mx, mn, scale, bias, x2nc, xh2, xl2, pooled);

  // ---- edge block 3: C=128 -> O=256 (MFMA knn + conv)
  sq_kernel<128><<<64, 256, 0, stream>>>(x2nc, sq);
  for (int it = 0; it < 4; ++it) {
    dist_mfma<128><<<2048, 256, 0, stream>>>(xh2, xl2, sq, nd, it * 2);
    knn_select<<<1024, 64, 0, stream>>>(nd, idxb, it * 2);
  }
  edge_mfma<128, 256><<<BN / 4, 256, 0, stream>>>(xh2, xl2, idxb, wlh3, wll3, dh3, dl3,
                                                  mx, mn, psum, psq);
  stats_part<256, 4096><<<64, 256, 0, stream>>>(psum, psq, pp, pq);
  stats_final<256><<<4, 64, 0, stream>>>(pp, pq, g3, b3, scale, bias);
  apply_kernel<256, 192, false><<<256, 256, 0, stream>>>(mx, mn, scale, bias, nullptr, nullptr, nullptr, pooled);

  // ---- head
  fc_kernel<448, true, true><<<1024, 64, 0, stream>>>(pooled, L1, h, 1024);
  fc_kernel<1024, false, false><<<2500, 64, 0, stream>>>(h, L2, out, 2500);
}

// Round 6
// 1247.642 us; speedup vs baseline: 1.6835x; 1.6835x over previous
//
#include <hip/hip_runtime.h>
#include <hip/hip_bf16.h>
#include <float.h>

#define K_NN 20
#define EPS 1e-5f
#define SLOPE 0.2f
constexpr int Bsz = 8;
constexpr int Npts = 2048;
constexpr int NQ = 8;            // layer-1 knn candidate-quadrant split
constexpr int BN = Bsz * Npts;   // 16384

typedef __attribute__((ext_vector_type(8))) short short8v;
typedef __attribute__((ext_vector_type(4))) float f32x4;

__device__ __forceinline__ float dot4(float4 a, float4 b) {
  return a.x*b.x + a.y*b.y + a.z*b.z + a.w*b.w;
}
// order-preserving float<->uint encoding for atomicMax pooling (exact, deterministic)
__device__ __forceinline__ unsigned encf(float f) {
  unsigned u = __float_as_uint(f);
  return (u & 0x80000000u) ? ~u : (u | 0x80000000u);
}
__device__ __forceinline__ float decf(unsigned e) {
  unsigned u = (e & 0x80000000u) ? (e & 0x7fffffffu) : ~e;
  return __uint_as_float(u);
}
// bf16 split helpers (RNE)
__device__ __forceinline__ unsigned short f2bf(float x) {
  unsigned u = __float_as_uint(x);
  unsigned r = (u + 0x7fffu + ((u >> 16) & 1u)) >> 16;
  return (unsigned short)r;
}
__device__ __forceinline__ float bf2f(unsigned short h) {
  return __uint_as_float((unsigned)h << 16);
}
__device__ __forceinline__ f32x4 mfma16(short8v a, short8v b, f32x4 c) {
  return __builtin_amdgcn_mfma_f32_16x16x32_bf16(a, b, c, 0, 0, 0);
}

// ---------------------------------------------------------------- sq of rows
template<int C>
__global__ __launch_bounds__(256) void sq_kernel(const float* __restrict__ xt,
                                                 float* __restrict__ sq) {
  int p = blockIdx.x * 256 + threadIdx.x;
  if (p >= BN) return;
  const float* r = xt + (size_t)p * C;
  float s = 0.f;
  if constexpr (C % 4 == 0) {
    for (int c4 = 0; c4 < C / 4; ++c4) { float4 v = *(const float4*)(r + c4 * 4); s += dot4(v, v); }
  } else {
    #pragma unroll
    for (int c = 0; c < C; ++c) { float v = r[c]; s += v * v; }
  }
  sq[p] = s;
}

// ------------------------------------------------- layer-1 knn partial top-k (C=3)
template<int C, int MT>
__global__ __launch_bounds__(256) void knn_part(const float* __restrict__ xt,
    const float* __restrict__ sq, float* __restrict__ pval, int* __restrict__ pidx) {
  constexpr int MQ = Npts / NQ;
  __shared__ __align__(16) float chk[MT][C];
  __shared__ float csq[MT];
  const int t = threadIdx.x, w = t >> 6, l = t & 63;
  const int rowblk = blockIdx.x / NQ;
  const int q = blockIdx.x - rowblk * NQ;
  const int p0 = rowblk * 256;
  const int b = p0 / Npts;
  const int myrow = p0 + w * 64 + l;

  float cr[C];
  #pragma unroll
  for (int c = 0; c < C; ++c) cr[c] = xt[(size_t)myrow * C + c];
  const float sqn = sq[myrow];

  float vals[K_NN]; int ids[K_NN];
  #pragma unroll
  for (int i = 0; i < K_NN; ++i) { vals[i] = -FLT_MAX; ids[i] = 0; }

  const int mbase = q * MQ;
  for (int m0 = mbase; m0 < mbase + MQ; m0 += MT) {
    __syncthreads();
    const float* s2 = xt + ((size_t)b * Npts + m0) * C;
    for (int e = t; e < MT * C; e += 256) chk[e / C][e - (e / C) * C] = s2[e];
    for (int e = t; e < MT; e += 256) csq[e] = sq[b * Npts + m0 + e];
    __syncthreads();
    for (int j = 0; j < MT; ++j) {
      float dt = 0.f;
      #pragma unroll
      for (int c = 0; c < C; ++c) dt += cr[c] * chk[j][c];
      float nd = 2.f * dt - sqn - csq[j];
      if (nd > vals[K_NN - 1]) {          // strict: ties keep earlier (lower) index
        vals[K_NN - 1] = nd; ids[K_NN - 1] = m0 + j;
        #pragma unroll
        for (int i = K_NN - 1; i >= 1; --i) {
          if (vals[i] > vals[i - 1]) {
            float tv = vals[i]; vals[i] = vals[i-1]; vals[i-1] = tv;
            int ti = ids[i]; ids[i] = ids[i-1]; ids[i-1] = ti;
          }
        }
      }
    }
  }
  size_t base = ((size_t)q * BN + myrow) * K_NN;
  #pragma unroll
  for (int i = 0; i < K_NN; ++i) { pval[base + i] = vals[i]; pidx[base + i] = ids[i]; }
}

// ------------------------------------------------- merge NQ sorted lists -> top-20
__global__ __launch_bounds__(256) void knn_merge(const float* __restrict__ pval,
    const int* __restrict__ pidx, int* __restrict__ idxout) {
  int p = blockIdx.x * 256 + threadIdx.x;
  if (p >= BN) return;
  float vals[K_NN]; int ids[K_NN];
  size_t base = (size_t)p * K_NN;
  #pragma unroll
  for (int i = 0; i < K_NN; ++i) { vals[i] = pval[base + i]; ids[i] = pidx[base + i]; }
  for (int q = 1; q < NQ; ++q) {
    size_t b2 = ((size_t)q * BN + p) * K_NN;
    #pragma unroll
    for (int i = 0; i < K_NN; ++i) {
      float v = pval[b2 + i];
      if (v <= vals[K_NN - 1]) break;
      int m = pidx[b2 + i];
      vals[K_NN - 1] = v; ids[K_NN - 1] = m;
      #pragma unroll
      for (int r = K_NN - 1; r >= 1; --r) {
        if (vals[r] > vals[r - 1]) {
          float tv = vals[r]; vals[r] = vals[r-1]; vals[r-1] = tv;
          int ti = ids[r]; ids[r] = ids[r-1]; ids[r-1] = ti;
        }
      }
    }
  }
  int* op = idxout + (size_t)p * K_NN;
  #pragma unroll
  for (int i = 0; i < K_NN; ++i) op[i] = ids[i];
}

// ------------------------------------------------- fused MFMA knn (dist + top-20)
// Block owns 64 query rows of one batch. A-frags register-resident; loops 32
// candidate tiles: MFMA 64x64 raw inner products -> LDS -> 4 scanners/row keep
// sorted top-20; final 4-way merge writes idx. Distances never touch HBM.
template<int C>
__global__ __launch_bounds__(256, 1) void knn_fused(
    const unsigned short* __restrict__ xh, const unsigned short* __restrict__ xl,
    const float* __restrict__ sq, int* __restrict__ idxout) {
  constexpr int KS = C / 32;
  __shared__ __align__(16) char smem[40960];
  float (*dist)[66] = (float(*)[66])smem;                  // 64x66 f32 = 16.9KB
  float (*lv)[K_NN] = (float(*)[K_NN])smem;                // overlay after loop
  int   (*li)[K_NN] = (int(*)[K_NN])(smem + 256 * K_NN * 4);
  const int b = blockIdx.x >> 5, nt = blockIdx.x & 31;
  const int n0 = nt * 64;
  const int t = threadIdx.x, l = t & 63, wv = t >> 6, l15 = l & 15, grp = l >> 4;
  const unsigned short* xbh = xh + (size_t)b * Npts * C;
  const unsigned short* xbl = xl + (size_t)b * Npts * C;
  const float* sqb = sq + b * Npts;

  short8v ah[4 * KS], al[4 * KS];
  #pragma unroll
  for (int rt = 0; rt < 4; ++rt)
    #pragma unroll
    for (int ks = 0; ks < KS; ++ks) {
      const size_t a = (size_t)(n0 + rt * 16 + l15) * C + ks * 32 + grp * 8;
      ah[rt * KS + ks] = *(const short8v*)(xbh + a);
      al[rt * KS + ks] = *(const short8v*)(xbl + a);
    }

  const int srow = t >> 2, ss = t & 3;
  const float sqn = sqb[n0 + srow];
  float vals[K_NN]; int ids[K_NN];
  #pragma unroll
  for (int i = 0; i < K_NN; ++i) { vals[i] = -FLT_MAX; ids[i] = 0; }

  for (int mt = 0; mt < 32; ++mt) {
    const int m0 = mt * 64;
    const int brow = m0 + wv * 16 + l15;
    f32x4 acc[4];
    #pragma unroll
    for (int rt = 0; rt < 4; ++rt) acc[rt] = (f32x4){0.f, 0.f, 0.f, 0.f};
    #pragma unroll
    for (int ks = 0; ks < KS; ++ks) {
      const size_t boff = (size_t)brow * C + ks * 32 + grp * 8;
      const short8v bh = *(const short8v*)(xbh + boff);
      const short8v bl = *(const short8v*)(xbl + boff);
      #pragma unroll
      for (int rt = 0; rt < 4; ++rt) {
        acc[rt] = mfma16(ah[rt * KS + ks], bh, acc[rt]);
        acc[rt] = mfma16(al[rt * KS + ks], bh, acc[rt]);
        acc[rt] = mfma16(ah[rt * KS + ks], bl, acc[rt]);
      }
    }
    __syncthreads();                       // previous scan done
    #pragma unroll
    for (int rt = 0; rt < 4; ++rt)
      #pragma unroll
      for (int r = 0; r < 4; ++r)
        dist[rt * 16 + grp * 4 + r][wv * 16 + l15] = 2.f * acc[rt][r];
    __syncthreads();
    for (int j = 0; j < 16; ++j) {
      const int gcol = m0 + ss * 16 + j;
      float v = dist[srow][ss * 16 + j] - sqn - sqb[gcol];
      if (gcol == n0 + srow) v = 0.f;      // exact self-distance
      if (v > vals[K_NN - 1]) {            // strict: ties keep earlier index
        vals[K_NN - 1] = v; ids[K_NN - 1] = gcol;
        #pragma unroll
        for (int r = K_NN - 1; r >= 1; --r) {
          if (vals[r] > vals[r - 1]) {
            float tv = vals[r]; vals[r] = vals[r-1]; vals[r-1] = tv;
            int ti = ids[r]; ids[r] = ids[r-1]; ids[r-1] = ti;
          }
        }
      }
    }
  }
  __syncthreads();
  #pragma unroll
  for (int i = 0; i < K_NN; ++i) { lv[t][i] = vals[i]; li[t][i] = ids[i]; }
  __syncthreads();
  if (t < 64) {
    float mv[K_NN]; int mi[K_NN];
    #pragma unroll
    for (int i = 0; i < K_NN; ++i) { mv[i] = lv[t * 4][i]; mi[i] = li[t * 4][i]; }
    for (int s2 = 1; s2 < 4; ++s2) {
      #pragma unroll
      for (int i = 0; i < K_NN; ++i) {
        const float v = lv[t * 4 + s2][i];
        if (v <= mv[K_NN - 1]) break;      // sorted source -> rest also fail
        const int m = li[t * 4 + s2][i];
        mv[K_NN - 1] = v; mi[K_NN - 1] = m;
        #pragma unroll
        for (int r = K_NN - 1; r >= 1; --r) {
          if (mv[r] > mv[r - 1]) {
            float tv = mv[r]; mv[r] = mv[r-1]; mv[r-1] = tv;
            int ti = mi[r]; mi[r] = mi[r-1]; mi[r-1] = ti;
          }
        }
      }
    }
    int* op = idxout + ((size_t)(b * Npts + n0 + t)) * K_NN;
    #pragma unroll
    for (int i = 0; i < K_NN; ++i) op[i] = mi[i];
  }
}

// ------------------------------------------------- prep: [W_lo; W_hi-W_lo] bf16 split
template<int C, int O>
__global__ __launch_bounds__(256) void prep_w(const float* __restrict__ W,
    unsigned short* __restrict__ wh, unsigned short* __restrict__ wl) {
  int i = blockIdx.x * 256 + threadIdx.x;
  if (i >= 2 * O * C) return;
  int j = i / C, c = i - j * C;
  float v = (j < O) ? W[(size_t)j * 2 * C + c]
                    : (W[(size_t)(j - O) * 2 * C + C + c] - W[(size_t)(j - O) * 2 * C + c]);
  unsigned short h = f2bf(v);
  wh[i] = h; wl[i] = f2bf(v - bf2f(h));
}

// ------------------------------------------------- dense GEMM Z = X * Wcat^T (split-3)
// Z[BN][N2], cols 0..O-1 = W_lo part (z), cols O..2O-1 = D part (base).
template<int C, int N2>
__global__ __launch_bounds__(256) void zgemm(
    const unsigned short* __restrict__ xh, const unsigned short* __restrict__ xl,
    const unsigned short* __restrict__ wh, const unsigned short* __restrict__ wl,
    float* __restrict__ Z, int r0) {
  constexpr int KS = C / 32;
  constexpr int CB = N2 / 64;
  const int nb = blockIdx.x / CB, cb = blockIdx.x - nb * CB;
  const int ln0 = nb * 64;
  const int t = threadIdx.x, l = t & 63, wv = t >> 6, l15 = l & 15, grp = l >> 4;
  const int col = cb * 64 + wv * 16 + l15;
  f32x4 acc[4];
  #pragma unroll
  for (int rt = 0; rt < 4; ++rt) acc[rt] = (f32x4){0.f, 0.f, 0.f, 0.f};
  #pragma unroll
  for (int ks = 0; ks < KS; ++ks) {
    const int krd = ks * 32 + grp * 8;
    const short8v bh = *(const short8v*)(wh + (size_t)col * C + krd);
    const short8v bl = *(const short8v*)(wl + (size_t)col * C + krd);
    #pragma unroll
    for (int rt = 0; rt < 4; ++rt) {
      const size_t arow = (size_t)(r0 + ln0 + rt * 16 + l15) * C + krd;
      const short8v a_h = *(const short8v*)(xh + arow);
      const short8v a_l = *(const short8v*)(xl + arow);
      acc[rt] = mfma16(a_h, bh, acc[rt]);
      acc[rt] = mfma16(a_l, bh, acc[rt]);
      acc[rt] = mfma16(a_h, bl, acc[rt]);
    }
  }
  #pragma unroll
  for (int rt = 0; rt < 4; ++rt)
    #pragma unroll
    for (int r = 0; r < 4; ++r)
      Z[(size_t)(ln0 + rt * 16 + grp * 4 + r) * N2 + col] = acc[rt][r];
}

// ------------------------------------------------- neighbor gather-reduce
// y_k = Z[nb_k][o] + Z[p][O+o]; emits per-point max/min (NC layout) + block stats.
template<int O, int NPP>
__global__ __launch_bounds__(256) void nbr_reduce(
    const float* __restrict__ Z, const int* __restrict__ idx,
    float* __restrict__ mx, float* __restrict__ mn,
    float* __restrict__ psum, float* __restrict__ psq, int r0) {
  constexpr int PPB = 256 / O;
  constexpr int O2 = 2 * O;
  const int t = threadIdx.x;
  const int o = t % O;
  const int sub = t / O;
  float ls = 0.f, lq = 0.f;
  for (int it = 0; it < NPP / PPB; ++it) {
    const int p = r0 + blockIdx.x * NPP + it * PPB + sub;
    const int bbase = (p >> 11) << 11;            // batch start (global row)
    const int* ip = idx + (size_t)p * K_NN;
    const float base = Z[(size_t)(p - r0) * O2 + O + o];
    float vmx = -FLT_MAX, vmn = FLT_MAX;
    #pragma unroll
    for (int k = 0; k < K_NN; ++k) {
      const int nbrow = bbase + ip[k] - r0;       // Z-local row
      const float y = Z[(size_t)nbrow * O2 + o] + base;
      ls += y; lq = fmaf(y, y, lq);
      vmx = fmaxf(vmx, y); vmn = fminf(vmn, y);
    }
    mx[(size_t)p * O + o] = vmx;
    mn[(size_t)p * O + o] = vmn;
  }
  if constexpr (PPB > 1) {
    __shared__ float s1[256], s2[256];
    s1[t] = ls; s2[t] = lq;
    __syncthreads();
    if (sub == 0) {
      psum[(size_t)blockIdx.x * O + o] = ls + s1[t + O];
      psq [(size_t)blockIdx.x * O + o] = lq + s2[t + O];
    }
  } else {
    psum[(size_t)blockIdx.x * O + o] = ls;
    psq [(size_t)blockIdx.x * O + o] = lq;
  }
}

// ------------------------------------------------- vector edge conv (layer 1, C=3)
template<int C, int O, int G, int NPG, int CPT>
__global__ __launch_bounds__(256) void edge_kernel(const float* __restrict__ xt,
    const int* __restrict__ idx, const float* __restrict__ W,
    float* __restrict__ mx, float* __restrict__ mn,
    float* __restrict__ psum, float* __restrict__ psq) {
  constexpr int WP = O / (64 * CPT);
  constexpr int TPB = 64 * WP * NPG;
  constexpr int PPG = G / NPG;
  static_assert(TPB == 256, "block must be 256 threads");
  __shared__ __align__(16) float pts[G][K_NN + 1][C];
  __shared__ int ids[G][K_NN + 1];
  __shared__ float shps[NPG][O];
  __shared__ float shpq[NPG][O];
  const int t = threadIdx.x;
  const int p0 = blockIdx.x * G;
  const int b = p0 / Npts;

  for (int e = t; e < G * (K_NN + 1); e += TPB) {
    int g = e / (K_NN + 1), j = e - g * (K_NN + 1);
    ids[g][j] = (j == 0) ? (p0 + g) : (b * Npts + idx[(size_t)(p0 + g) * K_NN + (j - 1)]);
  }
  __syncthreads();
  for (int e = t; e < G * (K_NN + 1) * C; e += TPB) {
    int g = e / ((K_NN + 1) * C), rem = e - g * ((K_NN + 1) * C);
    int j = rem / C, c = rem - j * C;
    pts[g][j][c] = xt[(size_t)ids[g][j] * C + c];
  }
  __syncthreads();

  const int w = t >> 6, l = t & 63;
  const int pg = w / WP, wp = w - pg * WP;
  const int o0 = wp * 64 + l;
  float ls0 = 0.f, lq0 = 0.f;

  for (int it = 0; it < PPG; ++it) {
    const int g = pg * PPG + it;
    float yk0[K_NN];
    float u0 = 0.f, v0 = 0.f;
    #pragma unroll
    for (int k = 0; k < K_NN; ++k) yk0[k] = 0.f;
    const float* W0 = W + (size_t)o0 * (2 * C);
    #pragma unroll
    for (int c = 0; c < C; ++c) {
      const float wl = W0[c], whv = W0[C + c], ccv = pts[g][0][c];
      u0 += wl * ccv; v0 += whv * ccv;
      #pragma unroll
      for (int k = 0; k < K_NN; ++k) yk0[k] += wl * pts[g][k + 1][c];
    }
    const int n = p0 + g - b * Npts;
    const size_t obase = ((size_t)b * Npts + n) * O;
    const float base = v0 - u0;
    float vmx = -FLT_MAX, vmn = FLT_MAX;
    #pragma unroll
    for (int k = 0; k < K_NN; ++k) {
      float y = yk0[k] + base;
      ls0 += y; lq0 += y * y;
      vmx = fmaxf(vmx, y); vmn = fminf(vmn, y);
    }
    mx[obase + o0] = vmx; mn[obase + o0] = vmn;
  }

  shps[pg][o0] = ls0; shpq[pg][o0] = lq0;
  __syncthreads();
  if (t < O) {
    float s = 0.f, qq = 0.f;
    #pragma unroll
    for (int i = 0; i < NPG; ++i) { s += shps[i][t]; qq += shpq[i][t]; }
    psum[(size_t)blockIdx.x * O + t] = s;
    psq [(size_t)blockIdx.x * O + t] = qq;
  }
}

// ------------------------------------------------- two-stage BN stats
template<int O, int NBLK>
__global__ __launch_bounds__(256) void stats_part(const float* __restrict__ psum,
    const float* __restrict__ psq, double* __restrict__ pp, double* __restrict__ pq) {
  constexpr int NS = 16;
  constexpr int SL = NBLK / NS;
  const int l = threadIdx.x & 63, w = threadIdx.x >> 6;
  const int os = blockIdx.x % (O / 64), sl = blockIdx.x / (O / 64);
  const int o = os * 64 + l;
  double s = 0.0, ss = 0.0;
  for (int i = sl * SL + w; i < (sl + 1) * SL; i += 4) {
    s  += (double)psum[(size_t)i * O + o];
    ss += (double)psq [(size_t)i * O + o];
  }
  __shared__ double sh[2][4][64];
  sh[0][w][l] = s; sh[1][w][l] = ss;
  __syncthreads();
  if (w == 0) {
    s  = sh[0][0][l] + sh[0][1][l] + sh[0][2][l] + sh[0][3][l];
    ss = sh[1][0][l] + sh[1][1][l] + sh[1][2][l] + sh[1][3][l];
    pp[(size_t)sl * O + o] = s;
    pq[(size_t)sl * O + o] = ss;
  }
}

template<int O>
__global__ __launch_bounds__(64) void stats_final(const double* __restrict__ pp,
    const double* __restrict__ pq,
    const float* __restrict__ gamma, const float* __restrict__ beta,
    float* __restrict__ scale, float* __restrict__ bias) {
  const int o = blockIdx.x * 64 + threadIdx.x;
  double s = 0.0, ss = 0.0;
  #pragma unroll
  for (int sl = 0; sl < 16; ++sl) { s += pp[(size_t)sl * O + o]; ss += pq[(size_t)sl * O + o]; }
  double cnt = (double)Bsz * Npts * K_NN;
  double m = s / cnt;
  double var = ss / cnt - m * m;
  float g = gamma[o];
  float sc = g * rsqrtf((float)var + EPS);
  scale[o] = sc;
  bias[o] = beta[o] - (float)m * sc;
}

// ------------------------------------------------- reset pooled accumulators
__global__ __launch_bounds__(256) void reset_pool(unsigned* __restrict__ pooled) {
  int i = blockIdx.x * 256 + threadIdx.x;
  if (i < Bsz * 448) pooled[i] = 0u;   // 0 < encf(f) for all finite f
}

// ------------------------------------------------- normalize + lrelu + pool + bf16 split
template<int O, int COFF, bool WNC>
__global__ __launch_bounds__(256) void apply_kernel(const float* __restrict__ mx,
    const float* __restrict__ mn, const float* __restrict__ scale,
    const float* __restrict__ bias, float* __restrict__ xnc,
    unsigned short* __restrict__ xh, unsigned short* __restrict__ xl,
    unsigned* __restrict__ pooled) {
  constexpr int OT = O / 64;
  constexpr int NCH = Npts / 256;
  const int bid = blockIdx.x;
  const int nchunk = bid % NCH;
  const int ot = (bid / NCH) % OT;
  const int b = bid / (NCH * OT);
  const int l = threadIdx.x & 63, w = threadIdx.x >> 6;
  const int o = ot * 64 + l;
  const float sc = scale[o], bs = bias[o];
  const bool pos = (sc >= 0.f);
  float vmax = -FLT_MAX;
  const int n0 = nchunk * 256;
  for (int i = 0; i < 64; ++i) {
    int n = n0 + w + i * 4;
    size_t ix = ((size_t)b * Npts + n) * O + o;
    float raw = pos ? mx[ix] : mn[ix];   // max for +scale, min for -scale
    float y = raw * sc + bs;
    y = (y >= 0.f) ? y : SLOPE * y;
    if constexpr (WNC) {
      xnc[ix] = y;
      unsigned short h = f2bf(y);
      xh[ix] = h;
      xl[ix] = f2bf(y - bf2f(h));
    }
    vmax = fmaxf(vmax, y);
  }
  __shared__ float sh[4][64];
  sh[w][l] = vmax;
  __syncthreads();
  if (w == 0) {
    float m = fmaxf(fmaxf(sh[0][l], sh[1][l]), fmaxf(sh[2][l], sh[3][l]));
    atomicMax(pooled + b * 448 + COFF + o, encf(m));
  }
}

// ------------------------------------------------- FC layers
template<int CIN, bool LRELU, bool DECODE>
__global__ __launch_bounds__(64) void fc_kernel(const void* __restrict__ inv,
    const float* __restrict__ Wt, float* __restrict__ out, int JO) {
  int j = blockIdx.x;
  const float* wr = Wt + (size_t)j * CIN;
  float acc[Bsz];
  #pragma unroll
  for (int b = 0; b < Bsz; ++b) acc[b] = 0.f;
  for (int c = threadIdx.x; c < CIN; c += 64) {
    float wv = wr[c];
    #pragma unroll
    for (int b = 0; b < Bsz; ++b) {
      float x;
      if constexpr (DECODE) x = decf(((const unsigned*)inv)[b * CIN + c]);
      else                  x = ((const float*)inv)[b * CIN + c];
      acc[b] += x * wv;
    }
  }
  #pragma unroll
  for (int b = 0; b < Bsz; ++b) {
    float v = acc[b];
    #pragma unroll
    for (int w = 32; w > 0; w >>= 1) v += __shfl_down(v, w);
    if (threadIdx.x == 0) {
      if (LRELU) v = (v >= 0.f) ? v : SLOPE * v;
      out[b * JO + j] = v;
    }
  }
}

// ================================================================ launch
extern "C" void kernel_launch(void* const* d_in, const int* in_sizes, int n_in,
                              void* d_out, int out_size, void* d_ws, size_t ws_size,
                              hipStream_t stream) {
  const float* x   = (const float*)d_in[0];
  const float* W1  = (const float*)d_in[1];
  const float* g1  = (const float*)d_in[2];
  const float* b1  = (const float*)d_in[3];
  const float* W2  = (const float*)d_in[4];
  const float* g2  = (const float*)d_in[5];
  const float* b2  = (const float*)d_in[6];
  const float* W3  = (const float*)d_in[7];
  const float* g3  = (const float*)d_in[8];
  const float* b3  = (const float*)d_in[9];
  const float* L1  = (const float*)d_in[10];
  const float* L2  = (const float*)d_in[11];
  float* out = (float*)d_out;

  float* ws = (float*)d_ws;
  size_t off = 0;
  float* sq    = ws + off; off += BN;
  int*   idxb  = (int*)(ws + off); off += (size_t)BN * K_NN;
  float* mx    = ws + off; off += (size_t)BN * 256;
  float* mn    = ws + off; off += (size_t)BN * 256;
  float* Z     = ws + off; off += (size_t)BN * 256;          // 16.8MB (2-pass for L3)
  float* psum  = ws + off; off += (size_t)2048 * 256;
  float* psq   = ws + off; off += (size_t)2048 * 256;
  off = (off + 1) & ~(size_t)1;   // 8B align for doubles
  double* pp   = (double*)(ws + off); off += 16 * 256 * 2;
  double* pq   = (double*)(ws + off); off += 16 * 256 * 2;
  float* scale = ws + off; off += 256;
  float* bias  = ws + off; off += 256;
  float* x1nc  = ws + off; off += (size_t)BN * 64;
  float* x2nc  = ws + off; off += (size_t)BN * 128;
  unsigned short* xh1 = (unsigned short*)(ws + off); off += (size_t)BN * 64 / 2;
  unsigned short* xl1 = (unsigned short*)(ws + off); off += (size_t)BN * 64 / 2;
  unsigned short* xh2 = (unsigned short*)(ws + off); off += (size_t)BN * 128 / 2;
  unsigned short* xl2 = (unsigned short*)(ws + off); off += (size_t)BN * 128 / 2;
  unsigned* pooled = (unsigned*)(ws + off); off += Bsz * 448;
  float* h     = ws + off; off += Bsz * 1024;
  unsigned short* wch2 = (unsigned short*)(ws + off); off += 256 * 64 / 2;
  unsigned short* wcl2 = (unsigned short*)(ws + off); off += 256 * 64 / 2;
  unsigned short* wch3 = (unsigned short*)(ws + off); off += 512 * 128 / 2;
  unsigned short* wcl3 = (unsigned short*)(ws + off); off += 512 * 128 / 2;
  // layer-1 knn partial lists overlay mx/mn (disjoint lifetimes)
  float* pval = mx;
  int*   pidx = (int*)mn;

  reset_pool<<<14, 256, 0, stream>>>(pooled);
  prep_w<64, 128><<<(2 * 128 * 64 + 255) / 256, 256, 0, stream>>>(W2, wch2, wcl2);
  prep_w<128, 256><<<(2 * 256 * 128 + 255) / 256, 256, 0, stream>>>(W3, wch3, wcl3);

  // ---- edge block 1: C=3 -> O=64 (fp32 vector knn + conv)
  sq_kernel<3><<<64, 256, 0, stream>>>(x, sq);
  knn_part<3, 64><<<(BN / 256) * NQ, 256, 0, stream>>>(x, sq, pval, pidx);
  knn_merge<<<64, 256, 0, stream>>>(pval, pidx, idxb);
  edge_kernel<3, 64, 16, 4, 1><<<BN / 16, 256, 0, stream>>>(x, idxb, W1, mx, mn, psum, psq);
  stats_part<64, 1024><<<16, 256, 0, stream>>>(psum, psq, pp, pq);
  stats_final<64><<<1, 64, 0, stream>>>(pp, pq, g1, b1, scale, bias);
  apply_kernel<64, 0, true><<<64, 256, 0, stream>>>(mx, mn, scale, bias, x1nc, xh1, xl1, pooled);

  // ---- edge block 2: C=64 -> O=128 (fused knn + Z-GEMM + gather-reduce)
  sq_kernel<64><<<64, 256, 0, stream>>>(x1nc, sq);
  knn_fused<64><<<Bsz * 32, 256, 0, stream>>>(xh1, xl1, sq, idxb);
  zgemm<64, 256><<<(BN / 64) * 4, 256, 0, stream>>>(xh1, xl1, wch2, wcl2, Z, 0);
  nbr_reduce<128, 16><<<BN / 16, 256, 0, stream>>>(Z, idxb, mx, mn, psum, psq, 0);
  stats_part<128, 1024><<<32, 256, 0, stream>>>(psum, psq, pp, pq);
  stats_final<128><<<2, 64, 0, stream>>>(pp, pq, g2, b2, scale, bias);
  apply_kernel<128, 64, true><<<128, 256, 0, stream>>>(mx, mn, scale, bias, x2nc, xh2, xl2, pooled);

  // ---- edge block 3: C=128 -> O=256 (fused knn + 2-pass Z-GEMM + gather-reduce)
  sq_kernel<128><<<64, 256, 0, stream>>>(x2nc, sq);
  knn_fused<128><<<Bsz * 32, 256, 0, stream>>>(xh2, xl2, sq, idxb);
  for (int pass = 0; pass < 2; ++pass) {
    const int r0 = pass * (BN / 2);
    zgemm<128, 512><<<(BN / 2 / 64) * 8, 256, 0, stream>>>(xh2, xl2, wch3, wcl3, Z, r0);
    nbr_reduce<256, 8><<<BN / 2 / 8, 256, 0, stream>>>(Z, idxb, mx, mn,
        psum + (size_t)pass * 1024 * 256, psq + (size_t)pass * 1024 * 256, r0);
  }
  stats_part<256, 2048><<<64, 256, 0, stream>>>(psum, psq, pp, pq);
  stats_final<256><<<4, 64, 0, stream>>>(pp, pq, g3, b3, scale, bias);
  apply_kernel<256, 192, false><<<256, 256, 0, stream>>>(mx, mn, scale, bias, nullptr, nullptr, nullptr, pooled);

  // ---- head
  fc_kernel<448, true, true><<<1024, 64, 0, stream>>>(pooled, L1, h, 1024);
  fc_kernel<1024, false, false><<<2500, 64, 0, stream>>>(h, L2, out, 2500);
}

// Round 7
// 1237.583 us; speedup vs baseline: 1.6972x; 1.0081x over previous
//
#include <hip/hip_runtime.h>
#include <hip/hip_bf16.h>
#include <float.h>

#define K_NN 20
#define EPS 1e-5f
#define SLOPE 0.2f
constexpr int Bsz = 8;
constexpr int Npts = 2048;
constexpr int NQ = 8;            // layer-1 knn candidate-quadrant split
constexpr int BN = Bsz * Npts;   // 16384

typedef __attribute__((ext_vector_type(8))) short short8v;
typedef __attribute__((ext_vector_type(4))) float f32x4;

__device__ __forceinline__ float dot4(float4 a, float4 b) {
  return a.x*b.x + a.y*b.y + a.z*b.z + a.w*b.w;
}
// order-preserving float<->uint encoding for atomicMax pooling (exact, deterministic)
__device__ __forceinline__ unsigned encf(float f) {
  unsigned u = __float_as_uint(f);
  return (u & 0x80000000u) ? ~u : (u | 0x80000000u);
}
__device__ __forceinline__ float decf(unsigned e) {
  unsigned u = (e & 0x80000000u) ? (e & 0x7fffffffu) : ~e;
  return __uint_as_float(u);
}
// bf16 split helpers (RNE)
__device__ __forceinline__ unsigned short f2bf(float x) {
  unsigned u = __float_as_uint(x);
  unsigned r = (u + 0x7fffu + ((u >> 16) & 1u)) >> 16;
  return (unsigned short)r;
}
__device__ __forceinline__ float bf2f(unsigned short h) {
  return __uint_as_float((unsigned)h << 16);
}
__device__ __forceinline__ f32x4 mfma16(short8v a, short8v b, f32x4 c) {
  return __builtin_amdgcn_mfma_f32_16x16x32_bf16(a, b, c, 0, 0, 0);
}

// ---------------------------------------------------------------- sq of rows
template<int C>
__global__ __launch_bounds__(256) void sq_kernel(const float* __restrict__ xt,
                                                 float* __restrict__ sq) {
  int p = blockIdx.x * 256 + threadIdx.x;
  if (p >= BN) return;
  const float* r = xt + (size_t)p * C;
  float s = 0.f;
  if constexpr (C % 4 == 0) {
    for (int c4 = 0; c4 < C / 4; ++c4) { float4 v = *(const float4*)(r + c4 * 4); s += dot4(v, v); }
  } else {
    #pragma unroll
    for (int c = 0; c < C; ++c) { float v = r[c]; s += v * v; }
  }
  sq[p] = s;
}

// ------------------------------------------------- layer-1 knn partial top-k (C=3)
template<int C, int MT>
__global__ __launch_bounds__(256) void knn_part(const float* __restrict__ xt,
    const float* __restrict__ sq, float* __restrict__ pval, int* __restrict__ pidx) {
  constexpr int MQ = Npts / NQ;
  __shared__ __align__(16) float chk[MT][C];
  __shared__ float csq[MT];
  const int t = threadIdx.x, w = t >> 6, l = t & 63;
  const int rowblk = blockIdx.x / NQ;
  const int q = blockIdx.x - rowblk * NQ;
  const int p0 = rowblk * 256;
  const int b = p0 / Npts;
  const int myrow = p0 + w * 64 + l;

  float cr[C];
  #pragma unroll
  for (int c = 0; c < C; ++c) cr[c] = xt[(size_t)myrow * C + c];
  const float sqn = sq[myrow];

  float vals[K_NN]; int ids[K_NN];
  #pragma unroll
  for (int i = 0; i < K_NN; ++i) { vals[i] = -FLT_MAX; ids[i] = 0; }

  const int mbase = q * MQ;
  for (int m0 = mbase; m0 < mbase + MQ; m0 += MT) {
    __syncthreads();
    const float* s2 = xt + ((size_t)b * Npts + m0) * C;
    for (int e = t; e < MT * C; e += 256) chk[e / C][e - (e / C) * C] = s2[e];
    for (int e = t; e < MT; e += 256) csq[e] = sq[b * Npts + m0 + e];
    __syncthreads();
    for (int j = 0; j < MT; ++j) {
      float dt = 0.f;
      #pragma unroll
      for (int c = 0; c < C; ++c) dt += cr[c] * chk[j][c];
      float nd = 2.f * dt - sqn - csq[j];
      if (nd > vals[K_NN - 1]) {          // strict: ties keep earlier (lower) index
        vals[K_NN - 1] = nd; ids[K_NN - 1] = m0 + j;
        #pragma unroll
        for (int i = K_NN - 1; i >= 1; --i) {
          if (vals[i] > vals[i - 1]) {
            float tv = vals[i]; vals[i] = vals[i-1]; vals[i-1] = tv;
            int ti = ids[i]; ids[i] = ids[i-1]; ids[i-1] = ti;
          }
        }
      }
    }
  }
  size_t base = ((size_t)q * BN + myrow) * K_NN;
  #pragma unroll
  for (int i = 0; i < K_NN; ++i) { pval[base + i] = vals[i]; pidx[base + i] = ids[i]; }
}

// ------------------------------------------------- merge NQ sorted lists -> top-20
__global__ __launch_bounds__(256) void knn_merge(const float* __restrict__ pval,
    const int* __restrict__ pidx, int* __restrict__ idxout) {
  int p = blockIdx.x * 256 + threadIdx.x;
  if (p >= BN) return;
  float vals[K_NN]; int ids[K_NN];
  size_t base = (size_t)p * K_NN;
  #pragma unroll
  for (int i = 0; i < K_NN; ++i) { vals[i] = pval[base + i]; ids[i] = pidx[base + i]; }
  for (int q = 1; q < NQ; ++q) {
    size_t b2 = ((size_t)q * BN + p) * K_NN;
    #pragma unroll
    for (int i = 0; i < K_NN; ++i) {
      float v = pval[b2 + i];
      if (v <= vals[K_NN - 1]) break;
      int m = pidx[b2 + i];
      vals[K_NN - 1] = v; ids[K_NN - 1] = m;
      #pragma unroll
      for (int r = K_NN - 1; r >= 1; --r) {
        if (vals[r] > vals[r - 1]) {
          float tv = vals[r]; vals[r] = vals[r-1]; vals[r-1] = tv;
          int ti = ids[r]; ids[r] = ids[r-1]; ids[r-1] = ti;
        }
      }
    }
  }
  int* op = idxout + (size_t)p * K_NN;
  #pragma unroll
  for (int i = 0; i < K_NN; ++i) op[i] = ids[i];
}

// ------------------------------------------------- fused MFMA knn, register-direct
// 1 wave / 16 queries. Swapped operands: mfma(cand_frag, query_frag) puts 16
// candidates for ONE query in each lane's acc regs -> top-20 scan entirely in
// registers, no LDS, no barriers. 4 per-query lists (grp 0..3) merge via shfl.
template<int C>
__global__ __launch_bounds__(64) void knn_fused(
    const unsigned short* __restrict__ xh, const unsigned short* __restrict__ xl,
    const float* __restrict__ sq, int* __restrict__ idxout) {
  constexpr int KS = C / 32;
  const int b = blockIdx.x >> 7, qt = blockIdx.x & 127;
  const int q0 = qt * 16;
  const int l = threadIdx.x, l15 = l & 15, grp = l >> 4;
  const unsigned short* xbh = xh + (size_t)b * Npts * C;
  const unsigned short* xbl = xl + (size_t)b * Npts * C;
  const float* sqb = sq + b * Npts;
  const int qi = q0 + l15;

  short8v bh[KS], bl[KS];
  #pragma unroll
  for (int ks = 0; ks < KS; ++ks) {
    const size_t a = (size_t)qi * C + ks * 32 + grp * 8;
    bh[ks] = *(const short8v*)(xbh + a);
    bl[ks] = *(const short8v*)(xbl + a);
  }
  const float sqn = sqb[qi];

  float vals[K_NN]; int ids[K_NN];
  #pragma unroll
  for (int i = 0; i < K_NN; ++i) { vals[i] = -FLT_MAX; ids[i] = 0; }

  for (int mt = 0; mt < Npts / 64; ++mt) {
    const int m0 = mt * 64;
    f32x4 acc[4];
    #pragma unroll
    for (int rt = 0; rt < 4; ++rt) acc[rt] = (f32x4){0.f, 0.f, 0.f, 0.f};
    #pragma unroll
    for (int ks = 0; ks < KS; ++ks) {
      #pragma unroll
      for (int rt = 0; rt < 4; ++rt) {
        const size_t aoff = (size_t)(m0 + rt * 16 + l15) * C + ks * 32 + grp * 8;
        const short8v a_h = *(const short8v*)(xbh + aoff);
        const short8v a_l = *(const short8v*)(xbl + aoff);
        acc[rt] = mfma16(a_h, bh[ks], acc[rt]);
        acc[rt] = mfma16(a_l, bh[ks], acc[rt]);
        acc[rt] = mfma16(a_h, bl[ks], acc[rt]);
      }
    }
    // scan: lane holds cand rows {rt*16 + grp*4 + r} for query qi
    #pragma unroll
    for (int rt = 0; rt < 4; ++rt) {
      const int cb = m0 + rt * 16 + grp * 4;
      const float4 s4 = *(const float4*)(sqb + cb);
      const float sv[4] = {s4.x, s4.y, s4.z, s4.w};
      #pragma unroll
      for (int r = 0; r < 4; ++r) {
        const int cand = cb + r;
        float v = 2.f * acc[rt][r] - sqn - sv[r];
        if (cand == qi) v = 0.f;           // exact self-distance
        if (v > vals[K_NN - 1]) {          // strict: ties keep earlier index
          vals[K_NN - 1] = v; ids[K_NN - 1] = cand;
          #pragma unroll
          for (int i = K_NN - 1; i >= 1; --i) {
            if (vals[i] > vals[i - 1]) {
              float tv = vals[i]; vals[i] = vals[i-1]; vals[i-1] = tv;
              int ti = ids[i]; ids[i] = ids[i-1]; ids[i-1] = ti;
            }
          }
        }
      }
    }
  }

  // merge grp1..3 lists into grp0 (shfl; sources are untouched original lists)
  #pragma unroll
  for (int s2 = 1; s2 < 4; ++s2) {
    float ov[K_NN]; int oi[K_NN];
    #pragma unroll
    for (int i = 0; i < K_NN; ++i) {
      ov[i] = __shfl(vals[i], s2 * 16 + l15);
      oi[i] = __shfl(ids[i],  s2 * 16 + l15);
    }
    if (grp == 0) {
      #pragma unroll
      for (int i = 0; i < K_NN; ++i) {
        const float v = ov[i];
        if (v <= vals[K_NN - 1]) break;    // sorted source -> rest also fail
        vals[K_NN - 1] = v; ids[K_NN - 1] = oi[i];
        #pragma unroll
        for (int r = K_NN - 1; r >= 1; --r) {
          if (vals[r] > vals[r - 1]) {
            float tv = vals[r]; vals[r] = vals[r-1]; vals[r-1] = tv;
            int ti = ids[r]; ids[r] = ids[r-1]; ids[r-1] = ti;
          }
        }
      }
    }
  }
  if (grp == 0) {
    int* op = idxout + ((size_t)(b * Npts + qi)) * K_NN;
    #pragma unroll
    for (int i = 0; i < K_NN; ++i) op[i] = ids[i];
  }
}

// ------------------------------------------------- prep: [W_lo; W_hi-W_lo] bf16 split
template<int C, int O>
__global__ __launch_bounds__(256) void prep_w(const float* __restrict__ W,
    unsigned short* __restrict__ wh, unsigned short* __restrict__ wl) {
  int i = blockIdx.x * 256 + threadIdx.x;
  if (i >= 2 * O * C) return;
  int j = i / C, c = i - j * C;
  float v = (j < O) ? W[(size_t)j * 2 * C + c]
                    : (W[(size_t)(j - O) * 2 * C + C + c] - W[(size_t)(j - O) * 2 * C + c]);
  unsigned short h = f2bf(v);
  wh[i] = h; wl[i] = f2bf(v - bf2f(h));
}

// ------------------------------------------------- dense GEMM Z = X * Wcat^T (split-3)
// Z[BN][N2], cols 0..O-1 = W_lo part (z), cols O..2O-1 = D part (base).
template<int C, int N2>
__global__ __launch_bounds__(256) void zgemm(
    const unsigned short* __restrict__ xh, const unsigned short* __restrict__ xl,
    const unsigned short* __restrict__ wh, const unsigned short* __restrict__ wl,
    float* __restrict__ Z, int r0) {
  constexpr int KS = C / 32;
  constexpr int CB = N2 / 64;
  const int nb = blockIdx.x / CB, cb = blockIdx.x - nb * CB;
  const int ln0 = nb * 64;
  const int t = threadIdx.x, l = t & 63, wv = t >> 6, l15 = l & 15, grp = l >> 4;
  const int col = cb * 64 + wv * 16 + l15;
  f32x4 acc[4];
  #pragma unroll
  for (int rt = 0; rt < 4; ++rt) acc[rt] = (f32x4){0.f, 0.f, 0.f, 0.f};
  #pragma unroll
  for (int ks = 0; ks < KS; ++ks) {
    const int krd = ks * 32 + grp * 8;
    const short8v bh = *(const short8v*)(wh + (size_t)col * C + krd);
    const short8v bl = *(const short8v*)(wl + (size_t)col * C + krd);
    #pragma unroll
    for (int rt = 0; rt < 4; ++rt) {
      const size_t arow = (size_t)(r0 + ln0 + rt * 16 + l15) * C + krd;
      const short8v a_h = *(const short8v*)(xh + arow);
      const short8v a_l = *(const short8v*)(xl + arow);
      acc[rt] = mfma16(a_h, bh, acc[rt]);
      acc[rt] = mfma16(a_l, bh, acc[rt]);
      acc[rt] = mfma16(a_h, bl, acc[rt]);
    }
  }
  #pragma unroll
  for (int rt = 0; rt < 4; ++rt)
    #pragma unroll
    for (int r = 0; r < 4; ++r)
      Z[(size_t)(ln0 + rt * 16 + grp * 4 + r) * N2 + col] = acc[rt][r];
}

// ------------------------------------------------- neighbor gather-reduce
// y_k = Z[nb_k][o] + Z[p][O+o]; emits per-point max/min (NC layout) + block stats.
template<int O, int NPP>
__global__ __launch_bounds__(256) void nbr_reduce(
    const float* __restrict__ Z, const int* __restrict__ idx,
    float* __restrict__ mx, float* __restrict__ mn,
    float* __restrict__ psum, float* __restrict__ psq, int r0) {
  constexpr int PPB = 256 / O;
  constexpr int O2 = 2 * O;
  const int t = threadIdx.x;
  const int o = t % O;
  const int sub = t / O;
  float ls = 0.f, lq = 0.f;
  for (int it = 0; it < NPP / PPB; ++it) {
    const int p = r0 + blockIdx.x * NPP + it * PPB + sub;
    const int bbase = (p >> 11) << 11;            // batch start (global row)
    const int* ip = idx + (size_t)p * K_NN;
    const float base = Z[(size_t)(p - r0) * O2 + O + o];
    float vmx = -FLT_MAX, vmn = FLT_MAX;
    #pragma unroll
    for (int k = 0; k < K_NN; ++k) {
      const int nbrow = bbase + ip[k] - r0;       // Z-local row
      const float y = Z[(size_t)nbrow * O2 + o] + base;
      ls += y; lq = fmaf(y, y, lq);
      vmx = fmaxf(vmx, y); vmn = fminf(vmn, y);
    }
    mx[(size_t)p * O + o] = vmx;
    mn[(size_t)p * O + o] = vmn;
  }
  if constexpr (PPB > 1) {
    __shared__ float s1[256], s2[256];
    s1[t] = ls; s2[t] = lq;
    __syncthreads();
    if (sub == 0) {
      psum[(size_t)blockIdx.x * O + o] = ls + s1[t + O];
      psq [(size_t)blockIdx.x * O + o] = lq + s2[t + O];
    }
  } else {
    psum[(size_t)blockIdx.x * O + o] = ls;
    psq [(size_t)blockIdx.x * O + o] = lq;
  }
}

// ------------------------------------------------- vector edge conv (layer 1, C=3)
template<int C, int O, int G, int NPG, int CPT>
__global__ __launch_bounds__(256) void edge_kernel(const float* __restrict__ xt,
    const int* __restrict__ idx, const float* __restrict__ W,
    float* __restrict__ mx, float* __restrict__ mn,
    float* __restrict__ psum, float* __restrict__ psq) {
  constexpr int WP = O / (64 * CPT);
  constexpr int TPB = 64 * WP * NPG;
  constexpr int PPG = G / NPG;
  static_assert(TPB == 256, "block must be 256 threads");
  __shared__ __align__(16) float pts[G][K_NN + 1][C];
  __shared__ int ids[G][K_NN + 1];
  __shared__ float shps[NPG][O];
  __shared__ float shpq[NPG][O];
  const int t = threadIdx.x;
  const int p0 = blockIdx.x * G;
  const int b = p0 / Npts;

  for (int e = t; e < G * (K_NN + 1); e += TPB) {
    int g = e / (K_NN + 1), j = e - g * (K_NN + 1);
    ids[g][j] = (j == 0) ? (p0 + g) : (b * Npts + idx[(size_t)(p0 + g) * K_NN + (j - 1)]);
  }
  __syncthreads();
  for (int e = t; e < G * (K_NN + 1) * C; e += TPB) {
    int g = e / ((K_NN + 1) * C), rem = e - g * ((K_NN + 1) * C);
    int j = rem / C, c = rem - j * C;
    pts[g][j][c] = xt[(size_t)ids[g][j] * C + c];
  }
  __syncthreads();

  const int w = t >> 6, l = t & 63;
  const int pg = w / WP, wp = w - pg * WP;
  const int o0 = wp * 64 + l;
  float ls0 = 0.f, lq0 = 0.f;

  for (int it = 0; it < PPG; ++it) {
    const int g = pg * PPG + it;
    float yk0[K_NN];
    float u0 = 0.f, v0 = 0.f;
    #pragma unroll
    for (int k = 0; k < K_NN; ++k) yk0[k] = 0.f;
    const float* W0 = W + (size_t)o0 * (2 * C);
    #pragma unroll
    for (int c = 0; c < C; ++c) {
      const float wl = W0[c], whv = W0[C + c], ccv = pts[g][0][c];
      u0 += wl * ccv; v0 += whv * ccv;
      #pragma unroll
      for (int k = 0; k < K_NN; ++k) yk0[k] += wl * pts[g][k + 1][c];
    }
    const int n = p0 + g - b * Npts;
    const size_t obase = ((size_t)b * Npts + n) * O;
    const float base = v0 - u0;
    float vmx = -FLT_MAX, vmn = FLT_MAX;
    #pragma unroll
    for (int k = 0; k < K_NN; ++k) {
      float y = yk0[k] + base;
      ls0 += y; lq0 += y * y;
      vmx = fmaxf(vmx, y); vmn = fminf(vmn, y);
    }
    mx[obase + o0] = vmx; mn[obase + o0] = vmn;
  }

  shps[pg][o0] = ls0; shpq[pg][o0] = lq0;
  __syncthreads();
  if (t < O) {
    float s = 0.f, qq = 0.f;
    #pragma unroll
    for (int i = 0; i < NPG; ++i) { s += shps[i][t]; qq += shpq[i][t]; }
    psum[(size_t)blockIdx.x * O + t] = s;
    psq [(size_t)blockIdx.x * O + t] = qq;
  }
}

// ------------------------------------------------- two-stage BN stats
template<int O, int NBLK>
__global__ __launch_bounds__(256) void stats_part(const float* __restrict__ psum,
    const float* __restrict__ psq, double* __restrict__ pp, double* __restrict__ pq) {
  constexpr int NS = 16;
  constexpr int SL = NBLK / NS;
  const int l = threadIdx.x & 63, w = threadIdx.x >> 6;
  const int os = blockIdx.x % (O / 64), sl = blockIdx.x / (O / 64);
  const int o = os * 64 + l;
  double s = 0.0, ss = 0.0;
  for (int i = sl * SL + w; i < (sl + 1) * SL; i += 4) {
    s  += (double)psum[(size_t)i * O + o];
    ss += (double)psq [(size_t)i * O + o];
  }
  __shared__ double sh[2][4][64];
  sh[0][w][l] = s; sh[1][w][l] = ss;
  __syncthreads();
  if (w == 0) {
    s  = sh[0][0][l] + sh[0][1][l] + sh[0][2][l] + sh[0][3][l];
    ss = sh[1][0][l] + sh[1][1][l] + sh[1][2][l] + sh[1][3][l];
    pp[(size_t)sl * O + o] = s;
    pq[(size_t)sl * O + o] = ss;
  }
}

template<int O>
__global__ __launch_bounds__(64) void stats_final(const double* __restrict__ pp,
    const double* __restrict__ pq,
    const float* __restrict__ gamma, const float* __restrict__ beta,
    float* __restrict__ scale, float* __restrict__ bias) {
  const int o = blockIdx.x * 64 + threadIdx.x;
  double s = 0.0, ss = 0.0;
  #pragma unroll
  for (int sl = 0; sl < 16; ++sl) { s += pp[(size_t)sl * O + o]; ss += pq[(size_t)sl * O + o]; }
  double cnt = (double)Bsz * Npts * K_NN;
  double m = s / cnt;
  double var = ss / cnt - m * m;
  float g = gamma[o];
  float sc = g * rsqrtf((float)var + EPS);
  scale[o] = sc;
  bias[o] = beta[o] - (float)m * sc;
}

// ------------------------------------------------- reset pooled accumulators
__global__ __launch_bounds__(256) void reset_pool(unsigned* __restrict__ pooled) {
  int i = blockIdx.x * 256 + threadIdx.x;
  if (i < Bsz * 448) pooled[i] = 0u;   // 0 < encf(f) for all finite f
}

// ------------------------------------------------- normalize + lrelu + pool + bf16 split
template<int O, int COFF, bool WNC>
__global__ __launch_bounds__(256) void apply_kernel(const float* __restrict__ mx,
    const float* __restrict__ mn, const float* __restrict__ scale,
    const float* __restrict__ bias, float* __restrict__ xnc,
    unsigned short* __restrict__ xh, unsigned short* __restrict__ xl,
    unsigned* __restrict__ pooled) {
  constexpr int OT = O / 64;
  constexpr int NCH = Npts / 256;
  const int bid = blockIdx.x;
  const int nchunk = bid % NCH;
  const int ot = (bid / NCH) % OT;
  const int b = bid / (NCH * OT);
  const int l = threadIdx.x & 63, w = threadIdx.x >> 6;
  const int o = ot * 64 + l;
  const float sc = scale[o], bs = bias[o];
  const bool pos = (sc >= 0.f);
  float vmax = -FLT_MAX;
  const int n0 = nchunk * 256;
  for (int i = 0; i < 64; ++i) {
    int n = n0 + w + i * 4;
    size_t ix = ((size_t)b * Npts + n) * O + o;
    float raw = pos ? mx[ix] : mn[ix];   // max for +scale, min for -scale
    float y = raw * sc + bs;
    y = (y >= 0.f) ? y : SLOPE * y;
    if constexpr (WNC) {
      xnc[ix] = y;
      unsigned short h = f2bf(y);
      xh[ix] = h;
      xl[ix] = f2bf(y - bf2f(h));
    }
    vmax = fmaxf(vmax, y);
  }
  __shared__ float sh[4][64];
  sh[w][l] = vmax;
  __syncthreads();
  if (w == 0) {
    float m = fmaxf(fmaxf(sh[0][l], sh[1][l]), fmaxf(sh[2][l], sh[3][l]));
    atomicMax(pooled + b * 448 + COFF + o, encf(m));
  }
}

// ------------------------------------------------- FC layers
template<int CIN, bool LRELU, bool DECODE>
__global__ __launch_bounds__(64) void fc_kernel(const void* __restrict__ inv,
    const float* __restrict__ Wt, float* __restrict__ out, int JO) {
  int j = blockIdx.x;
  const float* wr = Wt + (size_t)j * CIN;
  float acc[Bsz];
  #pragma unroll
  for (int b = 0; b < Bsz; ++b) acc[b] = 0.f;
  for (int c = threadIdx.x; c < CIN; c += 64) {
    float wv = wr[c];
    #pragma unroll
    for (int b = 0; b < Bsz; ++b) {
      float x;
      if constexpr (DECODE) x = decf(((const unsigned*)inv)[b * CIN + c]);
      else                  x = ((const float*)inv)[b * CIN + c];
      acc[b] += x * wv;
    }
  }
  #pragma unroll
  for (int b = 0; b < Bsz; ++b) {
    float v = acc[b];
    #pragma unroll
    for (int w = 32; w > 0; w >>= 1) v += __shfl_down(v, w);
    if (threadIdx.x == 0) {
      if (LRELU) v = (v >= 0.f) ? v : SLOPE * v;
      out[b * JO + j] = v;
    }
  }
}

// ================================================================ launch
extern "C" void kernel_launch(void* const* d_in, const int* in_sizes, int n_in,
                              void* d_out, int out_size, void* d_ws, size_t ws_size,
                              hipStream_t stream) {
  const float* x   = (const float*)d_in[0];
  const float* W1  = (const float*)d_in[1];
  const float* g1  = (const float*)d_in[2];
  const float* b1  = (const float*)d_in[3];
  const float* W2  = (const float*)d_in[4];
  const float* g2  = (const float*)d_in[5];
  const float* b2  = (const float*)d_in[6];
  const float* W3  = (const float*)d_in[7];
  const float* g3  = (const float*)d_in[8];
  const float* b3  = (const float*)d_in[9];
  const float* L1  = (const float*)d_in[10];
  const float* L2  = (const float*)d_in[11];
  float* out = (float*)d_out;

  float* ws = (float*)d_ws;
  size_t off = 0;
  float* sq    = ws + off; off += BN;
  int*   idxb  = (int*)(ws + off); off += (size_t)BN * K_NN;
  float* mx    = ws + off; off += (size_t)BN * 256;
  float* mn    = ws + off; off += (size_t)BN * 256;
  float* Z     = ws + off; off += (size_t)BN * 256;          // 16.8MB (2-pass for L3)
  float* psum  = ws + off; off += (size_t)2048 * 256;
  float* psq   = ws + off; off += (size_t)2048 * 256;
  off = (off + 1) & ~(size_t)1;   // 8B align for doubles
  double* pp   = (double*)(ws + off); off += 16 * 256 * 2;
  double* pq   = (double*)(ws + off); off += 16 * 256 * 2;
  float* scale = ws + off; off += 256;
  float* bias  = ws + off; off += 256;
  float* x1nc  = ws + off; off += (size_t)BN * 64;
  float* x2nc  = ws + off; off += (size_t)BN * 128;
  unsigned short* xh1 = (unsigned short*)(ws + off); off += (size_t)BN * 64 / 2;
  unsigned short* xl1 = (unsigned short*)(ws + off); off += (size_t)BN * 64 / 2;
  unsigned short* xh2 = (unsigned short*)(ws + off); off += (size_t)BN * 128 / 2;
  unsigned short* xl2 = (unsigned short*)(ws + off); off += (size_t)BN * 128 / 2;
  unsigned* pooled = (unsigned*)(ws + off); off += Bsz * 448;
  float* h     = ws + off; off += Bsz * 1024;
  unsigned short* wch2 = (unsigned short*)(ws + off); off += 256 * 64 / 2;
  unsigned short* wcl2 = (unsigned short*)(ws + off); off += 256 * 64 / 2;
  unsigned short* wch3 = (unsigned short*)(ws + off); off += 512 * 128 / 2;
  unsigned short* wcl3 = (unsigned short*)(ws + off); off += 512 * 128 / 2;
  // layer-1 knn partial lists overlay mx/mn (disjoint lifetimes)
  float* pval = mx;
  int*   pidx = (int*)mn;

  reset_pool<<<14, 256, 0, stream>>>(pooled);
  prep_w<64, 128><<<(2 * 128 * 64 + 255) / 256, 256, 0, stream>>>(W2, wch2, wcl2);
  prep_w<128, 256><<<(2 * 256 * 128 + 255) / 256, 256, 0, stream>>>(W3, wch3, wcl3);

  // ---- edge block 1: C=3 -> O=64 (fp32 vector knn + conv)
  sq_kernel<3><<<64, 256, 0, stream>>>(x, sq);
  knn_part<3, 64><<<(BN / 256) * NQ, 256, 0, stream>>>(x, sq, pval, pidx);
  knn_merge<<<64, 256, 0, stream>>>(pval, pidx, idxb);
  edge_kernel<3, 64, 16, 4, 1><<<BN / 16, 256, 0, stream>>>(x, idxb, W1, mx, mn, psum, psq);
  stats_part<64, 1024><<<16, 256, 0, stream>>>(psum, psq, pp, pq);
  stats_final<64><<<1, 64, 0, stream>>>(pp, pq, g1, b1, scale, bias);
  apply_kernel<64, 0, true><<<64, 256, 0, stream>>>(mx, mn, scale, bias, x1nc, xh1, xl1, pooled);

  // ---- edge block 2: C=64 -> O=128 (fused knn + Z-GEMM + gather-reduce)
  sq_kernel<64><<<64, 256, 0, stream>>>(x1nc, sq);
  knn_fused<64><<<Bsz * 128, 64, 0, stream>>>(xh1, xl1, sq, idxb);
  zgemm<64, 256><<<(BN / 64) * 4, 256, 0, stream>>>(xh1, xl1, wch2, wcl2, Z, 0);
  nbr_reduce<128, 16><<<BN / 16, 256, 0, stream>>>(Z, idxb, mx, mn, psum, psq, 0);
  stats_part<128, 1024><<<32, 256, 0, stream>>>(psum, psq, pp, pq);
  stats_final<128><<<2, 64, 0, stream>>>(pp, pq, g2, b2, scale, bias);
  apply_kernel<128, 64, true><<<128, 256, 0, stream>>>(mx, mn, scale, bias, x2nc, xh2, xl2, pooled);

  // ---- edge block 3: C=128 -> O=256 (fused knn + 2-pass Z-GEMM + gather-reduce)
  sq_kernel<128><<<64, 256, 0, stream>>>(x2nc, sq);
  knn_fused<128><<<Bsz * 128, 64, 0, stream>>>(xh2, xl2, sq, idxb);
  for (int pass = 0; pass < 2; ++pass) {
    const int r0 = pass * (BN / 2);
    zgemm<128, 512><<<(BN / 2 / 64) * 8, 256, 0, stream>>>(xh2, xl2, wch3, wcl3, Z, r0);
    nbr_reduce<256, 8><<<BN / 2 / 8, 256, 0, stream>>>(Z, idxb, mx, mn,
        psum + (size_t)pass * 1024 * 256, psq + (size_t)pass * 1024 * 256, r0);
  }
  stats_part<256, 2048><<<64, 256, 0, stream>>>(psum, psq, pp, pq);
  stats_final<256><<<4, 64, 0, stream>>>(pp, pq, g3, b3, scale, bias);
  apply_kernel<256, 192, false><<<256, 256, 0, stream>>>(mx, mn, scale, bias, nullptr, nullptr, nullptr, pooled);

  // ---- head
  fc_kernel<448, true, true><<<1024, 64, 0, stream>>>(pooled, L1, h, 1024);
  fc_kernel<1024, false, false><<<2500, 64, 0, stream>>>(h, L2, out, 2500);
}